// Round 7
// baseline (281.093 us; speedup 1.0000x reference)
//
#include <hip/hip_runtime.h>
#include <hip/hip_bf16.h>

typedef unsigned short ushort_t;
typedef __attribute__((ext_vector_type(4))) short bf16x4_t;   // 4 x bf16 (2 VGPRs)
typedef __attribute__((ext_vector_type(8))) short short8;     // 8 x bf16
typedef __attribute__((ext_vector_type(4))) unsigned short ushort4_t;
typedef __attribute__((ext_vector_type(4))) float f32x4;
typedef __attribute__((ext_vector_type(2))) unsigned int uint2_t;
typedef __attribute__((ext_vector_type(4))) unsigned int uint4_t;

#define LOG2E 1.44269504088896340736f

__device__ __forceinline__ unsigned short f2bf(float f) {
    unsigned int u = __float_as_uint(f);
    u += 0x7fffu + ((u >> 16) & 1u);          // round-to-nearest-even
    return (unsigned short)(u >> 16);
}

__device__ __forceinline__ unsigned int pk2bf(float a, float b) {
    union { __hip_bfloat162 h2; unsigned int u; } cvt;
    cvt.h2 = __float22bfloat162_rn(make_float2(a, b));   // v_cvt_pk_bf16_f32
    return cvt.u;
}

__device__ __forceinline__ void gl_lds16(const ushort_t* g, ushort_t* l) {
    __builtin_amdgcn_global_load_lds(
        (const __attribute__((address_space(1))) unsigned int*)g,
        (__attribute__((address_space(3))) unsigned int*)l, 16, 0, 0);
}

// K=16 bf16 MFMA: A/B = 4 bf16 (2 VGPRs). S^T C-frag == PV A-frag for this shape.
__device__ __forceinline__ f32x4 mfma16(uint2_t a, uint2_t b, f32x4 c) {
    union { uint2_t u; bf16x4_t s; } ua, ub;
    ua.u = a; ub.u = b;
    return __builtin_amdgcn_mfma_f32_16x16x16bf16_1k(ua.s, ub.s, c, 0, 0, 0);
}

// ---------------------------------------------------------------------------
// Convert x (fp32 [8192][1024]) -> xb (bf16, same layout)
// ---------------------------------------------------------------------------
__global__ __launch_bounds__(256) void cvt_x(
    const float* __restrict__ x, ushort_t* __restrict__ xb)
{
    const size_t i = ((size_t)blockIdx.x * 256 + threadIdx.x) * 8;
    const float4 a = *(const float4*)(x + i);
    const float4 b = *(const float4*)(x + i + 4);
    uint4_t o;
    o[0] = pk2bf(a.x, a.y); o[1] = pk2bf(a.z, a.w);
    o[2] = pk2bf(b.x, b.y); o[3] = pk2bf(b.z, b.w);
    *(uint4_t*)(xb + i) = o;
}

// ---------------------------------------------------------------------------
// Transpose+convert w (fp32 [1024][3072]) -> wt (bf16 [3072][1024])
// ---------------------------------------------------------------------------
__global__ __launch_bounds__(256) void cvt_w(
    const float* __restrict__ w, ushort_t* __restrict__ wt)
{
    __shared__ ushort_t Ts[64][40];           // [n][k]
    const int k0 = blockIdx.x * 32, n0 = blockIdx.y * 64;
    const int tid = threadIdx.x;
    const int kr = tid >> 3, nc = (tid & 7) * 8;
    const float* g = w + (size_t)(k0 + kr) * 3072 + n0 + nc;
    const float4 a = *(const float4*)g;
    const float4 b = *(const float4*)(g + 4);
    const float vals[8] = {a.x, a.y, a.z, a.w, b.x, b.y, b.z, b.w};
#pragma unroll
    for (int j = 0; j < 8; ++j) Ts[nc + j][kr] = f2bf(vals[j]);
    __syncthreads();
    const int nr = tid >> 2, kc = (tid & 3) * 8;
    const short8 v = *(const short8*)&Ts[nr][kc];
    *(short8*)(wt + (size_t)(n0 + nr) * 1024 + k0 + kc) = v;
}

// ---------------------------------------------------------------------------
// qkv = xb @ wt^T + b.  BM=128, BN=128, BK=32 (R4 config).
// global_load_lds staging.  Epilogue: +bias; K,Q -> [bh][t][d]; V -> [bh][d][t].
// ---------------------------------------------------------------------------
__global__ __launch_bounds__(256) void qkv_gemm(
    const ushort_t* __restrict__ xb, const ushort_t* __restrict__ wt,
    const float* __restrict__ bq,
    ushort_t* __restrict__ kws, ushort_t* __restrict__ qws,
    ushort_t* __restrict__ vws)
{
    __shared__ ushort_t As[128 * 32];         // [m][k] packed
    __shared__ ushort_t Bs[128 * 32];         // [n][k] packed

    const int tid  = threadIdx.x;
    const int m0   = blockIdx.x * 128;
    const int n0   = blockIdx.y * 128;
    const int wv   = tid >> 6;
    const int lane = tid & 63;
    const int qr   = lane & 15;
    const int quad = lane >> 4;
    const int wm   = (wv >> 1) * 64;
    const int wn   = (wv & 1) * 64;

    const int lr   = lane >> 2;
    const int scol = (lane & 3) * 8;          // 8 bf16 = 16 B
    const ushort_t* gA = xb + (size_t)(m0 + wv*32 + lr) * 1024 + scol;
    const ushort_t* gB = wt + (size_t)(n0 + wv*32 + lr) * 1024 + scol;
    ushort_t* lA = As + wv * 32 * 32;
    ushort_t* lB = Bs + wv * 32 * 32;

    f32x4 acc[4][4];
#pragma unroll
    for (int i = 0; i < 4; ++i)
#pragma unroll
        for (int j = 0; j < 4; ++j) acc[i][j] = (f32x4){0.f, 0.f, 0.f, 0.f};

    for (int k0 = 0; k0 < 1024; k0 += 32) {
        __syncthreads();
        gl_lds16(gA + k0,             lA);
        gl_lds16(gA + k0 + 16 * 1024, lA + 16 * 32);
        gl_lds16(gB + k0,             lB);
        gl_lds16(gB + k0 + 16 * 1024, lB + 16 * 32);
        __syncthreads();

        short8 af[4], bfr[4];
#pragma unroll
        for (int i = 0; i < 4; ++i)
            af[i] = *(const short8*)&As[(wm + i*16 + qr) * 32 + quad * 8];
#pragma unroll
        for (int j = 0; j < 4; ++j)
            bfr[j] = *(const short8*)&Bs[(wn + j*16 + qr) * 32 + quad * 8];
#pragma unroll
        for (int i = 0; i < 4; ++i)
#pragma unroll
            for (int j = 0; j < 4; ++j)
                acc[i][j] = __builtin_amdgcn_mfma_f32_16x16x32_bf16(
                    af[i], bfr[j], acc[i][j], 0, 0, 0);
    }

    const int nbase = n0 + wn;
    const int sec   = nbase >> 10;            // 0=K, 1=Q, 2=V
    const int h     = (nbase & 1023) >> 6;

    if (sec == 2) {
#pragma unroll
        for (int j = 0; j < 4; ++j) {
            const float bias = bq[nbase + j*16 + qr];
            const int d = j*16 + qr;
#pragma unroll
            for (int i = 0; i < 4; ++i) {
                const int m  = m0 + wm + i*16 + quad*4;
                const int bb = m >> 11;
                const int tt = m & 2047;
                ushort4_t pk;
#pragma unroll
                for (int r = 0; r < 4; ++r) pk[r] = f2bf(acc[i][j][r] + bias);
                *(ushort4_t*)&vws[((size_t)(bb*16 + h)*64 + d)*2048 + tt] = pk;
            }
        }
    } else {
        ushort_t* __restrict__ dst = (sec == 0) ? kws : qws;
#pragma unroll
        for (int j = 0; j < 4; ++j) {
            const float bias = bq[nbase + j*16 + qr];
            const int d = j*16 + qr;
#pragma unroll
            for (int i = 0; i < 4; ++i) {
#pragma unroll
                for (int r = 0; r < 4; ++r) {
                    const int m  = m0 + wm + i*16 + quad*4 + r;
                    const int bb = m >> 11;
                    const int tt = m & 2047;
                    dst[(((size_t)(bb*16 + h)) * 2048 + tt) * 64 + d] =
                        f2bf(acc[i][j][r] + bias);
                }
            }
        }
    }
}

// ---------------------------------------------------------------------------
// Causal flash attention, work-stealing over 1024 (qt,bh) items.
// Double-buffered K/V (1 barrier/tile). Constant-max softmax. PV consumes the
// packed bf16 P straight from registers via 16x16x16 MFMA (no P LDS trip).
// ---------------------------------------------------------------------------
__global__ __launch_bounds__(256, 4) void attn_fwd(
    const ushort_t* __restrict__ kws, const ushort_t* __restrict__ qws,
    const ushort_t* __restrict__ vws, float* __restrict__ out,
    unsigned int* __restrict__ counter)
{
    constexpr int LDK = 72;                   // 64 + 8 pad (rows 16B-aligned)
    __shared__ ushort_t Ks[2][64 * LDK];      // [buf][key][d]
    __shared__ ushort_t Vs[2][64 * LDK];      // [buf][d][t]
    __shared__ int s_item;

    const int tid  = threadIdx.x;
    const int wv   = tid >> 6;
    const int lane = tid & 63;
    const int qr   = lane & 15;
    const int quad = lane >> 4;
    const int srow = tid >> 2;
    const int scol = (tid & 3) * 16;
    constexpr float SCL = 0.125f * LOG2E;     // 1/sqrt(64), log2 domain
    constexpr float CB  = 8.0f;               // fixed max bound (log2 units)

    for (;;) {
        if (tid == 0) s_item = (int)atomicAdd(counter, 1u);
        __syncthreads();
        const int item = s_item;
        if (item >= 1024) break;

        const int qt = 15 - (item >> 6);      // heavy tiles grabbed first
        const int bh = item & 63;
        const int q0 = qt * 128;
        const size_t bhT = (size_t)bh * 2048;
        const ushort_t* kbase = kws + bhT * 64;
        const ushort_t* vbase = vws + (size_t)bh * 64 * 2048;

        const int base = q0 + wv*32;
        const int qv0 = base + qr;            // softmax-domain q (q = lane&15)
        const int qv1 = qv0 + 16;

        const ushort_t* qg0 = qws + (bhT + qv0) * 64;
        const ushort_t* qg1 = qws + (bhT + qv1) * 64;
        const short8 Qb00 = *(const short8*)(qg0 + quad*8);
        const short8 Qb01 = *(const short8*)(qg0 + 32 + quad*8);
        const short8 Qb10 = *(const short8*)(qg1 + quad*8);
        const short8 Qb11 = *(const short8*)(qg1 + 32 + quad*8);

        float l_s[2] = {0.f, 0.f};
        f32x4 Oacc[2][4];
#pragma unroll
        for (int qs = 0; qs < 2; ++qs)
#pragma unroll
            for (int dt = 0; dt < 4; ++dt) Oacc[qs][dt] = (f32x4){0.f,0.f,0.f,0.f};

        const int nkt = 2*qt + 2;
        const int row_max = base + 31;

        // prologue: tile 0 -> regs -> buf0
        short8 kv0, kv1, vv0, vv1;
        {
            const ushort_t* kg = kbase + (size_t)srow * 64 + scol;
            const ushort_t* vg = vbase + (size_t)srow * 2048 + scol;
            kv0 = *(const short8*)(kg);     kv1 = *(const short8*)(kg + 8);
            vv0 = *(const short8*)(vg);     vv1 = *(const short8*)(vg + 8);
        }
        *(short8*)&Ks[0][srow * LDK + scol]     = kv0;
        *(short8*)&Ks[0][srow * LDK + scol + 8] = kv1;
        *(short8*)&Vs[0][srow * LDK + scol]     = vv0;
        *(short8*)&Vs[0][srow * LDK + scol + 8] = vv1;
        __syncthreads();

        for (int kt = 0; kt < nkt; ++kt) {
            const int k0 = kt * 64;
            const int cur = kt & 1;
            const bool more = (kt + 1 < nkt);
            if (more) {                       // issue next-tile loads (in flight)
                const ushort_t* kg = kbase + (size_t)(k0 + 64 + srow) * 64 + scol;
                const ushort_t* vg = vbase + (size_t)srow * 2048 + k0 + 64 + scol;
                kv0 = *(const short8*)(kg);   kv1 = *(const short8*)(kg + 8);
                vv0 = *(const short8*)(vg);   vv1 = *(const short8*)(vg + 8);
            }

            if (k0 <= row_max) {
                const ushort_t* Kc = Ks[cur];
                const ushort_t* Vc = Vs[cur];

                // S^T = K Q^T : C[m=key][n=q]
                f32x4 s0[4], s1[4];
#pragma unroll
                for (int t4 = 0; t4 < 4; ++t4) {
                    const short8 kf0 = *(const short8*)&Kc[(t4*16 + qr)*LDK + quad*8];
                    const short8 kf1 = *(const short8*)&Kc[(t4*16 + qr)*LDK + 32 + quad*8];
                    f32x4 a = (f32x4){0.f,0.f,0.f,0.f};
                    f32x4 b = (f32x4){0.f,0.f,0.f,0.f};
                    a = __builtin_amdgcn_mfma_f32_16x16x32_bf16(kf0, Qb00, a, 0,0,0);
                    a = __builtin_amdgcn_mfma_f32_16x16x32_bf16(kf1, Qb01, a, 0,0,0);
                    b = __builtin_amdgcn_mfma_f32_16x16x32_bf16(kf0, Qb10, b, 0,0,0);
                    b = __builtin_amdgcn_mfma_f32_16x16x32_bf16(kf1, Qb11, b, 0,0,0);
                    s0[t4] = a; s1[t4] = b;
                }

                // causal mask — wave-uniform branch, true on at most one tile
                if (k0 + 63 > base) {
#pragma unroll
                    for (int t4 = 0; t4 < 4; ++t4)
#pragma unroll
                        for (int r = 0; r < 4; ++r) {
                            const int key = k0 + t4*16 + quad*4 + r;
                            if (key > qv0) s0[t4][r] = -INFINITY;
                            if (key > qv1) s1[t4][r] = -INFINITY;
                        }
                }

                // constant-max softmax; P packed to bf16 IN REGISTERS.
                // pks[qs][t4] is simultaneously the S^T C-frag and the PV
                // A-frag for mfma 16x16x16 (keys t4*16 + quad*4 + r).
                uint2_t pks[2][4];
#pragma unroll
                for (int qs = 0; qs < 2; ++qs) {
                    f32x4* S = qs ? s1 : s0;
                    float ps = 0.f;
#pragma unroll
                    for (int t4 = 0; t4 < 4; ++t4) {
                        float p[4];
#pragma unroll
                        for (int r = 0; r < 4; ++r) {
                            p[r] = exp2f(__builtin_fmaf(S[t4][r], SCL, -CB));
                            ps += p[r];
                        }
                        pks[qs][t4][0] = pk2bf(p[0], p[1]);
                        pks[qs][t4][1] = pk2bf(p[2], p[3]);
                    }
                    l_s[qs] += ps;
                }

                // O += P V : B-frag = V[key][d] from Vs[d][t], k=quad*4..+3
#pragma unroll
                for (int dt = 0; dt < 4; ++dt) {
#pragma unroll
                    for (int t4 = 0; t4 < 4; ++t4) {
                        const uint2_t vf = *(const uint2_t*)
                            &Vc[(dt*16 + qr)*LDK + t4*16 + quad*4];
                        Oacc[0][dt] = mfma16(pks[0][t4], vf, Oacc[0][dt]);
                        Oacc[1][dt] = mfma16(pks[1][t4], vf, Oacc[1][dt]);
                    }
                }
            }

            if (more) {                       // stage tile kt+1 into other buf
                ushort_t* Kn = Ks[cur ^ 1];
                ushort_t* Vn = Vs[cur ^ 1];
                *(short8*)&Kn[srow * LDK + scol]     = kv0;
                *(short8*)&Kn[srow * LDK + scol + 8] = kv1;
                *(short8*)&Vn[srow * LDK + scol]     = vv0;
                *(short8*)&Vn[srow * LDK + scol + 8] = vv1;
            }
            __syncthreads();                  // buf ready / reads of cur done
        }

        // epilogue: reduce l across quads, store
        const int b = bh >> 4, h = bh & 15;
#pragma unroll
        for (int qs = 0; qs < 2; ++qs) {
            float lf = l_s[qs];
            lf += __shfl_xor(lf, 16);
            lf += __shfl_xor(lf, 32);
#pragma unroll
            for (int r = 0; r < 4; ++r) {
                const float lr  = __shfl(lf, quad*4 + r);
                const float inv = 1.f / lr;
                const int q = q0 + wv*32 + qs*16 + quad*4 + r;
                float* o = out + ((size_t)(b*2048 + q)) * 1024 + h*64;
#pragma unroll
                for (int dt = 0; dt < 4; ++dt) o[dt*16 + qr] = Oacc[qs][dt][r] * inv;
            }
        }
    }
}

extern "C" void kernel_launch(void* const* d_in, const int* in_sizes, int n_in,
                              void* d_out, int out_size, void* d_ws, size_t ws_size,
                              hipStream_t stream) {
    (void)in_sizes; (void)n_in; (void)out_size; (void)ws_size;
    const float* x  = (const float*)d_in[0];
    const float* w  = (const float*)d_in[1];
    const float* bq = (const float*)d_in[2];
    float* out = (float*)d_out;

    ushort_t* kws = (ushort_t*)d_ws;
    ushort_t* qws = kws + (size_t)8388608;
    ushort_t* vws = qws + (size_t)8388608;
    ushort_t* xb  = vws + (size_t)8388608;
    ushort_t* wt  = xb  + (size_t)8388608;
    unsigned int* counter = (unsigned int*)(wt + (size_t)3145728);

    (void)hipMemsetAsync(counter, 0, 4, stream);
    cvt_x<<<4096, 256, 0, stream>>>(x, xb);
    cvt_w<<<dim3(32, 48), 256, 0, stream>>>(w, wt);
    qkv_gemm<<<dim3(64, 24), 256, 0, stream>>>(xb, wt, bq, kws, qws, vws);
    attn_fwd<<<1024, 256, 0, stream>>>(kws, qws, vws, out, counter);
}

// Round 8
// 264.007 us; speedup vs baseline: 1.0647x; 1.0647x over previous
//
#include <hip/hip_runtime.h>
#include <hip/hip_bf16.h>

typedef unsigned short ushort_t;
typedef __attribute__((ext_vector_type(4))) short bf16x4_t;   // 4 x bf16 (2 VGPRs)
typedef __attribute__((ext_vector_type(8))) short short8;     // 8 x bf16
typedef __attribute__((ext_vector_type(4))) unsigned short ushort4_t;
typedef __attribute__((ext_vector_type(4))) float f32x4;
typedef __attribute__((ext_vector_type(2))) unsigned int uint2_t;
typedef __attribute__((ext_vector_type(4))) unsigned int uint4_t;

#define LOG2E 1.44269504088896340736f

__device__ __forceinline__ unsigned short f2bf(float f) {
    unsigned int u = __float_as_uint(f);
    u += 0x7fffu + ((u >> 16) & 1u);          // round-to-nearest-even
    return (unsigned short)(u >> 16);
}

__device__ __forceinline__ unsigned int pk2bf(float a, float b) {
    union { __hip_bfloat162 h2; unsigned int u; } cvt;
    cvt.h2 = __float22bfloat162_rn(make_float2(a, b));   // v_cvt_pk_bf16_f32
    return cvt.u;
}

__device__ __forceinline__ void gl_lds16(const ushort_t* g, ushort_t* l) {
    __builtin_amdgcn_global_load_lds(
        (const __attribute__((address_space(1))) unsigned int*)g,
        (__attribute__((address_space(3))) unsigned int*)l, 16, 0, 0);
}

// K=16 bf16 MFMA: A/B = 4 bf16 (2 VGPRs). S^T C-frag == PV A-frag for this shape.
__device__ __forceinline__ f32x4 mfma16(uint2_t a, uint2_t b, f32x4 c) {
    union { uint2_t u; bf16x4_t s; } ua, ub;
    ua.u = a; ub.u = b;
    return __builtin_amdgcn_mfma_f32_16x16x16bf16_1k(ua.s, ub.s, c, 0, 0, 0);
}

// ---------------------------------------------------------------------------
// Convert x (fp32 [8192][1024]) -> xb (bf16, same layout)
// ---------------------------------------------------------------------------
__global__ __launch_bounds__(256) void cvt_x(
    const float* __restrict__ x, ushort_t* __restrict__ xb)
{
    const size_t i = ((size_t)blockIdx.x * 256 + threadIdx.x) * 8;
    const float4 a = *(const float4*)(x + i);
    const float4 b = *(const float4*)(x + i + 4);
    uint4_t o;
    o[0] = pk2bf(a.x, a.y); o[1] = pk2bf(a.z, a.w);
    o[2] = pk2bf(b.x, b.y); o[3] = pk2bf(b.z, b.w);
    *(uint4_t*)(xb + i) = o;
}

// ---------------------------------------------------------------------------
// Transpose+convert w (fp32 [1024][3072]) -> wt (bf16 [3072][1024])
// ---------------------------------------------------------------------------
__global__ __launch_bounds__(256) void cvt_w(
    const float* __restrict__ w, ushort_t* __restrict__ wt)
{
    __shared__ ushort_t Ts[64][40];           // [n][k]
    const int k0 = blockIdx.x * 32, n0 = blockIdx.y * 64;
    const int tid = threadIdx.x;
    const int kr = tid >> 3, nc = (tid & 7) * 8;
    const float* g = w + (size_t)(k0 + kr) * 3072 + n0 + nc;
    const float4 a = *(const float4*)g;
    const float4 b = *(const float4*)(g + 4);
    const float vals[8] = {a.x, a.y, a.z, a.w, b.x, b.y, b.z, b.w};
#pragma unroll
    for (int j = 0; j < 8; ++j) Ts[nc + j][kr] = f2bf(vals[j]);
    __syncthreads();
    const int nr = tid >> 2, kc = (tid & 3) * 8;
    const short8 v = *(const short8*)&Ts[nr][kc];
    *(short8*)(wt + (size_t)(n0 + nr) * 1024 + k0 + kc) = v;
}

// ---------------------------------------------------------------------------
// qkv = xb @ wt^T + b.  BM=128, BN=128, BK=32.
// global_load_lds staging.  Epilogue: +bias; K,Q -> [bh][t][d]; V -> [bh][d][t].
// ---------------------------------------------------------------------------
__global__ __launch_bounds__(256) void qkv_gemm(
    const ushort_t* __restrict__ xb, const ushort_t* __restrict__ wt,
    const float* __restrict__ bq,
    ushort_t* __restrict__ kws, ushort_t* __restrict__ qws,
    ushort_t* __restrict__ vws)
{
    __shared__ ushort_t As[128 * 32];         // [m][k] packed
    __shared__ ushort_t Bs[128 * 32];         // [n][k] packed

    const int tid  = threadIdx.x;
    const int m0   = blockIdx.x * 128;
    const int n0   = blockIdx.y * 128;
    const int wv   = tid >> 6;
    const int lane = tid & 63;
    const int qr   = lane & 15;
    const int quad = lane >> 4;
    const int wm   = (wv >> 1) * 64;
    const int wn   = (wv & 1) * 64;

    const int lr   = lane >> 2;
    const int scol = (lane & 3) * 8;          // 8 bf16 = 16 B
    const ushort_t* gA = xb + (size_t)(m0 + wv*32 + lr) * 1024 + scol;
    const ushort_t* gB = wt + (size_t)(n0 + wv*32 + lr) * 1024 + scol;
    ushort_t* lA = As + wv * 32 * 32;
    ushort_t* lB = Bs + wv * 32 * 32;

    f32x4 acc[4][4];
#pragma unroll
    for (int i = 0; i < 4; ++i)
#pragma unroll
        for (int j = 0; j < 4; ++j) acc[i][j] = (f32x4){0.f, 0.f, 0.f, 0.f};

    for (int k0 = 0; k0 < 1024; k0 += 32) {
        __syncthreads();
        gl_lds16(gA + k0,             lA);
        gl_lds16(gA + k0 + 16 * 1024, lA + 16 * 32);
        gl_lds16(gB + k0,             lB);
        gl_lds16(gB + k0 + 16 * 1024, lB + 16 * 32);
        __syncthreads();

        short8 af[4], bfr[4];
#pragma unroll
        for (int i = 0; i < 4; ++i)
            af[i] = *(const short8*)&As[(wm + i*16 + qr) * 32 + quad * 8];
#pragma unroll
        for (int j = 0; j < 4; ++j)
            bfr[j] = *(const short8*)&Bs[(wn + j*16 + qr) * 32 + quad * 8];
#pragma unroll
        for (int i = 0; i < 4; ++i)
#pragma unroll
            for (int j = 0; j < 4; ++j)
                acc[i][j] = __builtin_amdgcn_mfma_f32_16x16x32_bf16(
                    af[i], bfr[j], acc[i][j], 0, 0, 0);
    }

    const int nbase = n0 + wn;
    const int sec   = nbase >> 10;            // 0=K, 1=Q, 2=V
    const int h     = (nbase & 1023) >> 6;

    if (sec == 2) {
#pragma unroll
        for (int j = 0; j < 4; ++j) {
            const float bias = bq[nbase + j*16 + qr];
            const int d = j*16 + qr;
#pragma unroll
            for (int i = 0; i < 4; ++i) {
                const int m  = m0 + wm + i*16 + quad*4;
                const int bb = m >> 11;
                const int tt = m & 2047;
                ushort4_t pk;
#pragma unroll
                for (int r = 0; r < 4; ++r) pk[r] = f2bf(acc[i][j][r] + bias);
                *(ushort4_t*)&vws[((size_t)(bb*16 + h)*64 + d)*2048 + tt] = pk;
            }
        }
    } else {
        ushort_t* __restrict__ dst = (sec == 0) ? kws : qws;
#pragma unroll
        for (int j = 0; j < 4; ++j) {
            const float bias = bq[nbase + j*16 + qr];
            const int d = j*16 + qr;
#pragma unroll
            for (int i = 0; i < 4; ++i) {
#pragma unroll
                for (int r = 0; r < 4; ++r) {
                    const int m  = m0 + wm + i*16 + quad*4 + r;
                    const int bb = m >> 11;
                    const int tt = m & 2047;
                    dst[(((size_t)(bb*16 + h)) * 2048 + tt) * 64 + d] =
                        f2bf(acc[i][j][r] + bias);
                }
            }
        }
    }
}

// ---------------------------------------------------------------------------
// Causal flash attention, work-stealing over 1024 (qt,bh) items.
// Double-buffered K/V (1 barrier/tile). Constant-max softmax fused per
// 16-key chunk (no S arrays -> low VGPR). PV consumes bf16 P from registers
// via 16x16x16 MFMA (no P LDS trip). Default launch bounds (no spill).
// ---------------------------------------------------------------------------
__global__ __launch_bounds__(256) void attn_fwd(
    const ushort_t* __restrict__ kws, const ushort_t* __restrict__ qws,
    const ushort_t* __restrict__ vws, float* __restrict__ out,
    unsigned int* __restrict__ counter)
{
    constexpr int LDK = 72;                   // 64 + 8 pad (rows 16B-aligned)
    __shared__ ushort_t Ks[2][64 * LDK];      // [buf][key][d]
    __shared__ ushort_t Vs[2][64 * LDK];      // [buf][d][t]
    __shared__ int s_item;

    const int tid  = threadIdx.x;
    const int wv   = tid >> 6;
    const int lane = tid & 63;
    const int qr   = lane & 15;
    const int quad = lane >> 4;
    const int srow = tid >> 2;
    const int scol = (tid & 3) * 16;
    constexpr float SCL = 0.125f * LOG2E;     // 1/sqrt(64), log2 domain
    constexpr float CB  = 8.0f;               // fixed max bound (log2 units)

    for (;;) {
        if (tid == 0) s_item = (int)atomicAdd(counter, 1u);
        __syncthreads();
        const int item = s_item;
        if (item >= 1024) break;

        const int qt = 15 - (item >> 6);      // heavy tiles grabbed first
        const int bh = item & 63;
        const int q0 = qt * 128;
        const size_t bhT = (size_t)bh * 2048;
        const ushort_t* kbase = kws + bhT * 64;
        const ushort_t* vbase = vws + (size_t)bh * 64 * 2048;

        const int base = q0 + wv*32;
        const int qv0 = base + qr;            // softmax-domain q (q = lane&15)
        const int qv1 = qv0 + 16;

        const ushort_t* qg0 = qws + (bhT + qv0) * 64;
        const ushort_t* qg1 = qws + (bhT + qv1) * 64;
        const short8 Qb00 = *(const short8*)(qg0 + quad*8);
        const short8 Qb01 = *(const short8*)(qg0 + 32 + quad*8);
        const short8 Qb10 = *(const short8*)(qg1 + quad*8);
        const short8 Qb11 = *(const short8*)(qg1 + 32 + quad*8);

        float l_s[2] = {0.f, 0.f};
        f32x4 Oacc[2][4];
#pragma unroll
        for (int qs = 0; qs < 2; ++qs)
#pragma unroll
            for (int dt = 0; dt < 4; ++dt) Oacc[qs][dt] = (f32x4){0.f,0.f,0.f,0.f};

        const int nkt = 2*qt + 2;
        const int row_max = base + 31;

        // prologue: tile 0 -> regs -> buf0
        short8 kv0, kv1, vv0, vv1;
        {
            const ushort_t* kg = kbase + (size_t)srow * 64 + scol;
            const ushort_t* vg = vbase + (size_t)srow * 2048 + scol;
            kv0 = *(const short8*)(kg);     kv1 = *(const short8*)(kg + 8);
            vv0 = *(const short8*)(vg);     vv1 = *(const short8*)(vg + 8);
        }
        *(short8*)&Ks[0][srow * LDK + scol]     = kv0;
        *(short8*)&Ks[0][srow * LDK + scol + 8] = kv1;
        *(short8*)&Vs[0][srow * LDK + scol]     = vv0;
        *(short8*)&Vs[0][srow * LDK + scol + 8] = vv1;
        __syncthreads();

        for (int kt = 0; kt < nkt; ++kt) {
            const int k0 = kt * 64;
            const int cur = kt & 1;
            const bool more = (kt + 1 < nkt);
            if (more) {                       // issue next-tile loads (in flight)
                const ushort_t* kg = kbase + (size_t)(k0 + 64 + srow) * 64 + scol;
                const ushort_t* vg = vbase + (size_t)srow * 2048 + k0 + 64 + scol;
                kv0 = *(const short8*)(kg);   kv1 = *(const short8*)(kg + 8);
                vv0 = *(const short8*)(vg);   vv1 = *(const short8*)(vg + 8);
            }

            if (k0 <= row_max) {
                const ushort_t* Kc = Ks[cur];
                const ushort_t* Vc = Vs[cur];
                const bool diag = (k0 + 63 > base);   // wave-uniform

                // Per 16-key chunk: S^T = K Q^T, mask, exp2, pack -> pks.
                // pks[qs][t4] is both the S^T C-frag and the PV A-frag.
                uint2_t pks[2][4];
                float ps0 = 0.f, ps1 = 0.f;
#pragma unroll
                for (int t4 = 0; t4 < 4; ++t4) {
                    const short8 kf0 = *(const short8*)&Kc[(t4*16 + qr)*LDK + quad*8];
                    const short8 kf1 = *(const short8*)&Kc[(t4*16 + qr)*LDK + 32 + quad*8];
                    f32x4 a = (f32x4){0.f,0.f,0.f,0.f};
                    f32x4 b = (f32x4){0.f,0.f,0.f,0.f};
                    a = __builtin_amdgcn_mfma_f32_16x16x32_bf16(kf0, Qb00, a, 0,0,0);
                    a = __builtin_amdgcn_mfma_f32_16x16x32_bf16(kf1, Qb01, a, 0,0,0);
                    b = __builtin_amdgcn_mfma_f32_16x16x32_bf16(kf0, Qb10, b, 0,0,0);
                    b = __builtin_amdgcn_mfma_f32_16x16x32_bf16(kf1, Qb11, b, 0,0,0);
                    if (diag) {
#pragma unroll
                        for (int r = 0; r < 4; ++r) {
                            const int key = k0 + t4*16 + quad*4 + r;
                            if (key > qv0) a[r] = -INFINITY;
                            if (key > qv1) b[r] = -INFINITY;
                        }
                    }
                    float p0[4], p1[4];
#pragma unroll
                    for (int r = 0; r < 4; ++r) {
                        p0[r] = exp2f(__builtin_fmaf(a[r], SCL, -CB));
                        p1[r] = exp2f(__builtin_fmaf(b[r], SCL, -CB));
                        ps0 += p0[r];
                        ps1 += p1[r];
                    }
                    pks[0][t4][0] = pk2bf(p0[0], p0[1]);
                    pks[0][t4][1] = pk2bf(p0[2], p0[3]);
                    pks[1][t4][0] = pk2bf(p1[0], p1[1]);
                    pks[1][t4][1] = pk2bf(p1[2], p1[3]);
                }
                l_s[0] += ps0;
                l_s[1] += ps1;

                // O += P V : B-frag = V[key][d] from Vs[d][t], k=quad*4..+3
#pragma unroll
                for (int dt = 0; dt < 4; ++dt) {
#pragma unroll
                    for (int t4 = 0; t4 < 4; ++t4) {
                        const uint2_t vf = *(const uint2_t*)
                            &Vc[(dt*16 + qr)*LDK + t4*16 + quad*4];
                        Oacc[0][dt] = mfma16(pks[0][t4], vf, Oacc[0][dt]);
                        Oacc[1][dt] = mfma16(pks[1][t4], vf, Oacc[1][dt]);
                    }
                }
            }

            if (more) {                       // stage tile kt+1 into other buf
                ushort_t* Kn = Ks[cur ^ 1];
                ushort_t* Vn = Vs[cur ^ 1];
                *(short8*)&Kn[srow * LDK + scol]     = kv0;
                *(short8*)&Kn[srow * LDK + scol + 8] = kv1;
                *(short8*)&Vn[srow * LDK + scol]     = vv0;
                *(short8*)&Vn[srow * LDK + scol + 8] = vv1;
            }
            __syncthreads();                  // buf ready / reads of cur done
        }

        // epilogue: reduce l across quads, store
        const int b = bh >> 4, h = bh & 15;
#pragma unroll
        for (int qs = 0; qs < 2; ++qs) {
            float lf = l_s[qs];
            lf += __shfl_xor(lf, 16);
            lf += __shfl_xor(lf, 32);
#pragma unroll
            for (int r = 0; r < 4; ++r) {
                const float lr  = __shfl(lf, quad*4 + r);
                const float inv = 1.f / lr;
                const int q = q0 + wv*32 + qs*16 + quad*4 + r;
                float* o = out + ((size_t)(b*2048 + q)) * 1024 + h*64;
#pragma unroll
                for (int dt = 0; dt < 4; ++dt) o[dt*16 + qr] = Oacc[qs][dt][r] * inv;
            }
        }
    }
}

extern "C" void kernel_launch(void* const* d_in, const int* in_sizes, int n_in,
                              void* d_out, int out_size, void* d_ws, size_t ws_size,
                              hipStream_t stream) {
    (void)in_sizes; (void)n_in; (void)out_size; (void)ws_size;
    const float* x  = (const float*)d_in[0];
    const float* w  = (const float*)d_in[1];
    const float* bq = (const float*)d_in[2];
    float* out = (float*)d_out;

    ushort_t* kws = (ushort_t*)d_ws;
    ushort_t* qws = kws + (size_t)8388608;
    ushort_t* vws = qws + (size_t)8388608;
    ushort_t* xb  = vws + (size_t)8388608;
    ushort_t* wt  = xb  + (size_t)8388608;
    unsigned int* counter = (unsigned int*)(wt + (size_t)3145728);

    (void)hipMemsetAsync(counter, 0, 4, stream);
    cvt_x<<<4096, 256, 0, stream>>>(x, xb);
    cvt_w<<<dim3(32, 48), 256, 0, stream>>>(w, wt);
    qkv_gemm<<<dim3(64, 24), 256, 0, stream>>>(xb, wt, bq, kws, qws, vws);
    attn_fwd<<<1024, 256, 0, stream>>>(kws, qws, vws, out, counter);
}

// Round 9
// 248.314 us; speedup vs baseline: 1.1320x; 1.0632x over previous
//
#include <hip/hip_runtime.h>
#include <hip/hip_bf16.h>

typedef unsigned short ushort_t;
typedef __attribute__((ext_vector_type(4))) short bf16x4_t;   // 4 x bf16 (2 VGPRs)
typedef __attribute__((ext_vector_type(8))) short short8;     // 8 x bf16
typedef __attribute__((ext_vector_type(4))) unsigned short ushort4_t;
typedef __attribute__((ext_vector_type(4))) float f32x4;
typedef __attribute__((ext_vector_type(2))) unsigned int uint2_t;
typedef __attribute__((ext_vector_type(4))) unsigned int uint4_t;

#define LOG2E 1.44269504088896340736f

__device__ __forceinline__ unsigned short f2bf(float f) {
    unsigned int u = __float_as_uint(f);
    u += 0x7fffu + ((u >> 16) & 1u);          // round-to-nearest-even
    return (unsigned short)(u >> 16);
}

__device__ __forceinline__ unsigned int pk2bf(float a, float b) {
    union { __hip_bfloat162 h2; unsigned int u; } cvt;
    cvt.h2 = __float22bfloat162_rn(make_float2(a, b));   // v_cvt_pk_bf16_f32
    return cvt.u;
}

__device__ __forceinline__ void gl_lds16(const ushort_t* g, ushort_t* l) {
    __builtin_amdgcn_global_load_lds(
        (const __attribute__((address_space(1))) unsigned int*)g,
        (__attribute__((address_space(3))) unsigned int*)l, 16, 0, 0);
}

// K=16 bf16 MFMA: A/B = 4 bf16 (2 VGPRs). S^T C-frag == PV A-frag for this shape.
__device__ __forceinline__ f32x4 mfma16(uint2_t a, uint2_t b, f32x4 c) {
    union { uint2_t u; bf16x4_t s; } ua, ub;
    ua.u = a; ub.u = b;
    return __builtin_amdgcn_mfma_f32_16x16x16bf16_1k(ua.s, ub.s, c, 0, 0, 0);
}

// ---------------------------------------------------------------------------
// Convert x (fp32 [8192][1024]) -> xb (bf16, same layout)
// ---------------------------------------------------------------------------
__global__ __launch_bounds__(256) void cvt_x(
    const float* __restrict__ x, ushort_t* __restrict__ xb)
{
    const size_t i = ((size_t)blockIdx.x * 256 + threadIdx.x) * 8;
    const float4 a = *(const float4*)(x + i);
    const float4 b = *(const float4*)(x + i + 4);
    uint4_t o;
    o[0] = pk2bf(a.x, a.y); o[1] = pk2bf(a.z, a.w);
    o[2] = pk2bf(b.x, b.y); o[3] = pk2bf(b.z, b.w);
    *(uint4_t*)(xb + i) = o;
}

// ---------------------------------------------------------------------------
// Transpose+convert w (fp32 [1024][3072]) -> wt (bf16 [3072][1024])
// ---------------------------------------------------------------------------
__global__ __launch_bounds__(256) void cvt_w(
    const float* __restrict__ w, ushort_t* __restrict__ wt)
{
    __shared__ ushort_t Ts[64][40];           // [n][k]
    const int k0 = blockIdx.x * 32, n0 = blockIdx.y * 64;
    const int tid = threadIdx.x;
    const int kr = tid >> 3, nc = (tid & 7) * 8;
    const float* g = w + (size_t)(k0 + kr) * 3072 + n0 + nc;
    const float4 a = *(const float4*)g;
    const float4 b = *(const float4*)(g + 4);
    const float vals[8] = {a.x, a.y, a.z, a.w, b.x, b.y, b.z, b.w};
#pragma unroll
    for (int j = 0; j < 8; ++j) Ts[nc + j][kr] = f2bf(vals[j]);
    __syncthreads();
    const int nr = tid >> 2, kc = (tid & 3) * 8;
    const short8 v = *(const short8*)&Ts[nr][kc];
    *(short8*)(wt + (size_t)(n0 + nr) * 1024 + k0 + kc) = v;
}

// ---------------------------------------------------------------------------
// qkv = xb @ wt^T + b.  BM=128, BN=128, BK=32.
// global_load_lds staging.  Epilogue: +bias; K,Q -> [bh][t][d]; V -> [bh][d][t].
// ---------------------------------------------------------------------------
__global__ __launch_bounds__(256) void qkv_gemm(
    const ushort_t* __restrict__ xb, const ushort_t* __restrict__ wt,
    const float* __restrict__ bq,
    ushort_t* __restrict__ kws, ushort_t* __restrict__ qws,
    ushort_t* __restrict__ vws)
{
    __shared__ ushort_t As[128 * 32];         // [m][k] packed
    __shared__ ushort_t Bs[128 * 32];         // [n][k] packed

    const int tid  = threadIdx.x;
    const int m0   = blockIdx.x * 128;
    const int n0   = blockIdx.y * 128;
    const int wv   = tid >> 6;
    const int lane = tid & 63;
    const int qr   = lane & 15;
    const int quad = lane >> 4;
    const int wm   = (wv >> 1) * 64;
    const int wn   = (wv & 1) * 64;

    const int lr   = lane >> 2;
    const int scol = (lane & 3) * 8;          // 8 bf16 = 16 B
    const ushort_t* gA = xb + (size_t)(m0 + wv*32 + lr) * 1024 + scol;
    const ushort_t* gB = wt + (size_t)(n0 + wv*32 + lr) * 1024 + scol;
    ushort_t* lA = As + wv * 32 * 32;
    ushort_t* lB = Bs + wv * 32 * 32;

    f32x4 acc[4][4];
#pragma unroll
    for (int i = 0; i < 4; ++i)
#pragma unroll
        for (int j = 0; j < 4; ++j) acc[i][j] = (f32x4){0.f, 0.f, 0.f, 0.f};

    for (int k0 = 0; k0 < 1024; k0 += 32) {
        __syncthreads();
        gl_lds16(gA + k0,             lA);
        gl_lds16(gA + k0 + 16 * 1024, lA + 16 * 32);
        gl_lds16(gB + k0,             lB);
        gl_lds16(gB + k0 + 16 * 1024, lB + 16 * 32);
        __syncthreads();

        short8 af[4], bfr[4];
#pragma unroll
        for (int i = 0; i < 4; ++i)
            af[i] = *(const short8*)&As[(wm + i*16 + qr) * 32 + quad * 8];
#pragma unroll
        for (int j = 0; j < 4; ++j)
            bfr[j] = *(const short8*)&Bs[(wn + j*16 + qr) * 32 + quad * 8];
#pragma unroll
        for (int i = 0; i < 4; ++i)
#pragma unroll
            for (int j = 0; j < 4; ++j)
                acc[i][j] = __builtin_amdgcn_mfma_f32_16x16x32_bf16(
                    af[i], bfr[j], acc[i][j], 0, 0, 0);
    }

    const int nbase = n0 + wn;
    const int sec   = nbase >> 10;            // 0=K, 1=Q, 2=V
    const int h     = (nbase & 1023) >> 6;

    if (sec == 2) {
#pragma unroll
        for (int j = 0; j < 4; ++j) {
            const float bias = bq[nbase + j*16 + qr];
            const int d = j*16 + qr;
#pragma unroll
            for (int i = 0; i < 4; ++i) {
                const int m  = m0 + wm + i*16 + quad*4;
                const int bb = m >> 11;
                const int tt = m & 2047;
                ushort4_t pk;
#pragma unroll
                for (int r = 0; r < 4; ++r) pk[r] = f2bf(acc[i][j][r] + bias);
                *(ushort4_t*)&vws[((size_t)(bb*16 + h)*64 + d)*2048 + tt] = pk;
            }
        }
    } else {
        ushort_t* __restrict__ dst = (sec == 0) ? kws : qws;
#pragma unroll
        for (int j = 0; j < 4; ++j) {
            const float bias = bq[nbase + j*16 + qr];
            const int d = j*16 + qr;
#pragma unroll
            for (int i = 0; i < 4; ++i) {
#pragma unroll
                for (int r = 0; r < 4; ++r) {
                    const int m  = m0 + wm + i*16 + quad*4 + r;
                    const int bb = m >> 11;
                    const int tt = m & 2047;
                    dst[(((size_t)(bb*16 + h)) * 2048 + tt) * 64 + d] =
                        f2bf(acc[i][j][r] + bias);
                }
            }
        }
    }
}

// ---------------------------------------------------------------------------
// Causal flash attention. Deterministic balanced pairing: block (bh, j)
// processes q-tiles j and 15-j -> exactly 34 k-tile iterations per block
// (no atomics, no tail). Double-buffered K/V, constant-max softmax fused per
// 16-key chunk, PV from registers via 16x16x16 MFMA.
// ---------------------------------------------------------------------------
__global__ __launch_bounds__(256) void attn_fwd(
    const ushort_t* __restrict__ kws, const ushort_t* __restrict__ qws,
    const ushort_t* __restrict__ vws, float* __restrict__ out)
{
    constexpr int LDK = 72;                   // 64 + 8 pad (rows 16B-aligned)
    __shared__ ushort_t Ks[2][64 * LDK];      // [buf][key][d]
    __shared__ ushort_t Vs[2][64 * LDK];      // [buf][d][t]

    const int tid  = threadIdx.x;
    const int wv   = tid >> 6;
    const int lane = tid & 63;
    const int qr   = lane & 15;
    const int quad = lane >> 4;
    const int srow = tid >> 2;
    const int scol = (tid & 3) * 16;
    constexpr float SCL = 0.125f * LOG2E;     // 1/sqrt(64), log2 domain
    constexpr float CB  = 8.0f;               // fixed max bound (log2 units)

    const int bh = (int)blockIdx.x >> 3;      // 8 pair-items per bh -> XCD spread
    const int jp = (int)blockIdx.x & 7;
    const size_t bhT = (size_t)bh * 2048;
    const ushort_t* kbase = kws + bhT * 64;
    const ushort_t* vbase = vws + (size_t)bh * 64 * 2048;
    const int b = bh >> 4, h = bh & 15;

#pragma unroll 1
    for (int part = 0; part < 2; ++part) {
        const int qt = part ? (15 - jp) : jp; // pair sums to 34 k-tiles always
        const int q0 = qt * 128;

        const int base = q0 + wv*32;
        const int qv0 = base + qr;            // softmax-domain q (q = lane&15)
        const int qv1 = qv0 + 16;

        const ushort_t* qg0 = qws + (bhT + qv0) * 64;
        const ushort_t* qg1 = qws + (bhT + qv1) * 64;
        const short8 Qb00 = *(const short8*)(qg0 + quad*8);
        const short8 Qb01 = *(const short8*)(qg0 + 32 + quad*8);
        const short8 Qb10 = *(const short8*)(qg1 + quad*8);
        const short8 Qb11 = *(const short8*)(qg1 + 32 + quad*8);

        float l_s[2] = {0.f, 0.f};
        f32x4 Oacc[2][4];
#pragma unroll
        for (int qs = 0; qs < 2; ++qs)
#pragma unroll
            for (int dt = 0; dt < 4; ++dt) Oacc[qs][dt] = (f32x4){0.f,0.f,0.f,0.f};

        const int nkt = 2*qt + 2;
        const int row_max = base + 31;

        // prologue: tile 0 -> regs -> buf0
        short8 kv0, kv1, vv0, vv1;
        {
            const ushort_t* kg = kbase + (size_t)srow * 64 + scol;
            const ushort_t* vg = vbase + (size_t)srow * 2048 + scol;
            kv0 = *(const short8*)(kg);     kv1 = *(const short8*)(kg + 8);
            vv0 = *(const short8*)(vg);     vv1 = *(const short8*)(vg + 8);
        }
        *(short8*)&Ks[0][srow * LDK + scol]     = kv0;
        *(short8*)&Ks[0][srow * LDK + scol + 8] = kv1;
        *(short8*)&Vs[0][srow * LDK + scol]     = vv0;
        *(short8*)&Vs[0][srow * LDK + scol + 8] = vv1;
        __syncthreads();

        for (int kt = 0; kt < nkt; ++kt) {
            const int k0 = kt * 64;
            const int cur = kt & 1;
            const bool more = (kt + 1 < nkt);
            if (more) {                       // issue next-tile loads (in flight)
                const ushort_t* kg = kbase + (size_t)(k0 + 64 + srow) * 64 + scol;
                const ushort_t* vg = vbase + (size_t)srow * 2048 + k0 + 64 + scol;
                kv0 = *(const short8*)(kg);   kv1 = *(const short8*)(kg + 8);
                vv0 = *(const short8*)(vg);   vv1 = *(const short8*)(vg + 8);
            }

            if (k0 <= row_max) {
                const ushort_t* Kc = Ks[cur];
                const ushort_t* Vc = Vs[cur];
                const bool diag = (k0 + 63 > base);   // wave-uniform

                // Per 16-key chunk: S^T = K Q^T, mask, exp2, pack -> pks.
                uint2_t pks[2][4];
                float ps0 = 0.f, ps1 = 0.f;
#pragma unroll
                for (int t4 = 0; t4 < 4; ++t4) {
                    const short8 kf0 = *(const short8*)&Kc[(t4*16 + qr)*LDK + quad*8];
                    const short8 kf1 = *(const short8*)&Kc[(t4*16 + qr)*LDK + 32 + quad*8];
                    f32x4 a = (f32x4){0.f,0.f,0.f,0.f};
                    f32x4 bfr = (f32x4){0.f,0.f,0.f,0.f};
                    a   = __builtin_amdgcn_mfma_f32_16x16x32_bf16(kf0, Qb00, a, 0,0,0);
                    a   = __builtin_amdgcn_mfma_f32_16x16x32_bf16(kf1, Qb01, a, 0,0,0);
                    bfr = __builtin_amdgcn_mfma_f32_16x16x32_bf16(kf0, Qb10, bfr, 0,0,0);
                    bfr = __builtin_amdgcn_mfma_f32_16x16x32_bf16(kf1, Qb11, bfr, 0,0,0);
                    if (diag) {
#pragma unroll
                        for (int r = 0; r < 4; ++r) {
                            const int key = k0 + t4*16 + quad*4 + r;
                            if (key > qv0) a[r]   = -INFINITY;
                            if (key > qv1) bfr[r] = -INFINITY;
                        }
                    }
                    float p0[4], p1[4];
#pragma unroll
                    for (int r = 0; r < 4; ++r) {
                        p0[r] = exp2f(__builtin_fmaf(a[r],   SCL, -CB));
                        p1[r] = exp2f(__builtin_fmaf(bfr[r], SCL, -CB));
                        ps0 += p0[r];
                        ps1 += p1[r];
                    }
                    pks[0][t4][0] = pk2bf(p0[0], p0[1]);
                    pks[0][t4][1] = pk2bf(p0[2], p0[3]);
                    pks[1][t4][0] = pk2bf(p1[0], p1[1]);
                    pks[1][t4][1] = pk2bf(p1[2], p1[3]);
                }
                l_s[0] += ps0;
                l_s[1] += ps1;

                // O += P V : B-frag = V[key][d] from Vs[d][t], k=quad*4..+3
#pragma unroll
                for (int dt = 0; dt < 4; ++dt) {
#pragma unroll
                    for (int t4 = 0; t4 < 4; ++t4) {
                        const uint2_t vf = *(const uint2_t*)
                            &Vc[(dt*16 + qr)*LDK + t4*16 + quad*4];
                        Oacc[0][dt] = mfma16(pks[0][t4], vf, Oacc[0][dt]);
                        Oacc[1][dt] = mfma16(pks[1][t4], vf, Oacc[1][dt]);
                    }
                }
            }

            if (more) {                       // stage tile kt+1 into other buf
                ushort_t* Kn = Ks[cur ^ 1];
                ushort_t* Vn = Vs[cur ^ 1];
                *(short8*)&Kn[srow * LDK + scol]     = kv0;
                *(short8*)&Kn[srow * LDK + scol + 8] = kv1;
                *(short8*)&Vn[srow * LDK + scol]     = vv0;
                *(short8*)&Vn[srow * LDK + scol + 8] = vv1;
            }
            __syncthreads();                  // buf ready / reads of cur done
        }

        // epilogue: reduce l across quads, store
#pragma unroll
        for (int qs = 0; qs < 2; ++qs) {
            float lf = l_s[qs];
            lf += __shfl_xor(lf, 16);
            lf += __shfl_xor(lf, 32);
#pragma unroll
            for (int r = 0; r < 4; ++r) {
                const float lr  = __shfl(lf, quad*4 + r);
                const float inv = 1.f / lr;
                const int q = q0 + wv*32 + qs*16 + quad*4 + r;
                float* o = out + ((size_t)(b*2048 + q)) * 1024 + h*64;
#pragma unroll
                for (int dt = 0; dt < 4; ++dt) o[dt*16 + qr] = Oacc[qs][dt][r] * inv;
            }
        }
    }
}

extern "C" void kernel_launch(void* const* d_in, const int* in_sizes, int n_in,
                              void* d_out, int out_size, void* d_ws, size_t ws_size,
                              hipStream_t stream) {
    (void)in_sizes; (void)n_in; (void)out_size; (void)ws_size;
    const float* x  = (const float*)d_in[0];
    const float* w  = (const float*)d_in[1];
    const float* bq = (const float*)d_in[2];
    float* out = (float*)d_out;

    ushort_t* kws = (ushort_t*)d_ws;
    ushort_t* qws = kws + (size_t)8388608;
    ushort_t* vws = qws + (size_t)8388608;
    ushort_t* xb  = vws + (size_t)8388608;
    ushort_t* wt  = xb  + (size_t)8388608;

    cvt_x<<<4096, 256, 0, stream>>>(x, xb);
    cvt_w<<<dim3(32, 48), 256, 0, stream>>>(w, wt);
    qkv_gemm<<<dim3(64, 24), 256, 0, stream>>>(xb, wt, bq, kws, qws, vws);
    attn_fwd<<<512, 256, 0, stream>>>(kws, qws, vws, out);
}